// Round 11
// baseline (239.338 us; speedup 1.0000x reference)
//
#include <hip/hip_runtime.h>
#include <hip/hip_bf16.h>

typedef __attribute__((ext_vector_type(8))) short short8;
typedef __attribute__((ext_vector_type(4))) float f32x4;

#define B_ 8
#define C_ 64
#define H_ 256
#define W_ 256
#define HW_ 65536
#define K_ 10
#define NS1 24
#define NS2 18
#define HP_ 258
#define WP_ 258
#define PXP_ (HP_*WP_)
#define SLABW 34
#define SLABR 10

static __device__ __forceinline__ unsigned short f2bf(float f) {
    __hip_bfloat16 hb = __float2bfloat16(f);
    return *(unsigned short*)&hb;
}
static __device__ __forceinline__ float bf2f(unsigned short u) {
    unsigned v = ((unsigned)u) << 16;
    float f;
    __builtin_memcpy(&f, &v, 4);
    return f;
}

// async global->LDS 16B (dest = wave-uniform base + lane*16, linear in tau)
static __device__ __forceinline__ void gload_lds16(const void* g, void* l) {
    __builtin_amdgcn_global_load_lds(
        (const __attribute__((address_space(1))) unsigned int*)(unsigned long long)g,
        (__attribute__((address_space(3))) unsigned int*)(unsigned int)(unsigned long long)l,
        16, 0, 0);
}

// ---------------------------------------------------------------------------
// Fragment-ordered, gamma-folded, expert-mixed weights + biases.
// W4_1: [b][24 steps][4 of][64 lane][8] bf16 (0..17 conv taps, 18..23 1x1)
// W4_2: [b][18 steps][4][64][8] bf16
// ---------------------------------------------------------------------------
__global__ void k_combine(const float* __restrict__ attn, const float* __restrict__ gamma,
                          const float* __restrict__ w1, const float* __restrict__ b1,
                          const float* __restrict__ w2, const float* __restrict__ b2,
                          const float* __restrict__ w16, const float* __restrict__ w168,
                          const float* __restrict__ w88,
                          unsigned short* __restrict__ W4_1, unsigned short* __restrict__ W4_2,
                          float* __restrict__ bias1, float* __restrict__ bias2) {
    const int N1 = B_ * NS1 * 2048;
    const int N2 = B_ * NS2 * 2048;
    int gid = blockIdx.x * 256 + threadIdx.x;
    if (gid < N1) {
        int b = gid / (NS1 * 2048);
        int r = gid - b * (NS1 * 2048);
        int s = r >> 11;
        int r2 = r & 2047;
        int of = r2 >> 9, l = (r2 >> 3) & 63, j = r2 & 7;
        int o = of * 16 + (l & 15);
        int g = l >> 4;
        float val;
        if (s < 18) {
            int t = s >> 1, h = s & 1;
            int c = h * 32 + g * 8 + j;
            float acc = 0.f;
            #pragma unroll
            for (int k = 0; k < K_; ++k)
                acc += attn[b * K_ + k] * w2[((size_t)(k * 64 + o) * 64 + c) * 9 + t];
            val = acc * gamma[b * 64 + o];
        } else {
            int e = s - 18;
            int m = e >> 1, h = e & 1;
            int c = h * 32 + g * 8 + j;
            const float* wm = (m == 0) ? w16 : (m == 1 ? w168 : w88);
            val = wm[o * 64 + c];
        }
        W4_1[gid] = f2bf(val);
    } else if (gid < N1 + N2) {
        int gid2 = gid - N1;
        int b = gid2 / (NS2 * 2048);
        int r = gid2 - b * (NS2 * 2048);
        int s = r >> 11;
        int r2 = r & 2047;
        int of = r2 >> 9, l = (r2 >> 3) & 63, j = r2 & 7;
        int o = of * 16 + (l & 15);
        int g = l >> 4;
        int t = s >> 1, h = s & 1;
        int c = h * 32 + g * 8 + j;
        float acc = 0.f;
        #pragma unroll
        for (int k = 0; k < K_; ++k)
            acc += attn[b * K_ + k] * w1[((size_t)(k * 64 + o) * 64 + c) * 9 + t];
        W4_2[gid2] = f2bf(acc * gamma[b * 64 + o]);
    } else if (gid < N1 + N2 + 1024) {
        int id2 = gid - N1 - N2;
        int b = id2 >> 7;
        int rest = id2 & 127;
        int o = rest >> 1;
        int which = rest & 1;
        const float* bb = which ? b1 : b2;
        float acc = 0.f;
        #pragma unroll
        for (int k = 0; k < K_; ++k) acc += attn[b * K_ + k] * bb[k * 64 + o];
        float v = acc * gamma[b * 64 + o];
        if (which) bias2[b * 64 + o] = v; else bias1[b * 64 + o] = v;
    }
}

// ---------------------------------------------------------------------------
// Zero halo borders of the padded X1p / Tp buffers.
// ---------------------------------------------------------------------------
__global__ void k_border(unsigned short* __restrict__ X1p, unsigned short* __restrict__ Tp) {
    int gid = blockIdx.x * 256 + threadIdx.x;
    if (gid >= 2 * B_ * 1028 * 8) return;
    int chunk = gid & 7;
    int rest = gid >> 3;
    int p = rest % 1028;
    int rb = rest / 1028;
    int buf = rb & 1, b = rb >> 1;
    int row, col;
    if (p < 258) { row = 0; col = p; }
    else if (p < 516) { row = 257; col = p - 258; }
    else if (p < 772) { row = p - 516 + 1; col = 0; }
    else { row = p - 772 + 1; col = 257; }
    unsigned short* base = (buf ? Tp : X1p) +
        ((size_t)b * PXP_ + (size_t)row * WP_ + col) * 64 + chunk * 8;
    *(short8*)base = (short8){0, 0, 0, 0, 0, 0, 0, 0};
}

// ---------------------------------------------------------------------------
// x [b][64][HW] f32  ->  X1p [b][258][258][64] bf16 (interior only)
// ---------------------------------------------------------------------------
__global__ __launch_bounds__(256) void k_prep(const float* __restrict__ x,
                                              unsigned short* __restrict__ X1p) {
    __shared__ float ls[64][65];
    const int b = blockIdx.y;
    const int px0 = blockIdx.x * 64;
    const int row = px0 >> 8;
    const int col0 = px0 & 255;
    const int t = threadIdx.x;
    for (int e = t; e < 4096; e += 256) {
        int ch = e >> 6, px = e & 63;
        ls[ch][px] = x[((size_t)b * 64 + ch) * HW_ + px0 + px];
    }
    __syncthreads();
    unsigned short* dst = X1p + ((size_t)b * PXP_ + (size_t)(row + 1) * WP_ + col0 + 1) * 64;
    for (int e = t; e < 4096; e += 256) {
        int ch = e & 63, px = e >> 6;
        dst[(size_t)px * 64 + ch] = f2bf(ls[ch][px]);
    }
}

// ---------------------------------------------------------------------------
// Implicit-GEMM conv3x3 via MFMA. Block: 256 thr / 4 FAT waves.
// Wave owns M=64 px (2 img rows x 32 w), N=64 o -> 16 MFMA per K-32 step.
// A: slab [10][34][64] bf16 (43.5 KB, global_load_lds) - ONLY LDS user.
// B: global->VGPR, 3-deep pipeline, per-step asm vmcnt fences ("memory"
// clobber pins per-step scheduling). NO barriers in the K-loop: slab is
// read-only after one prologue barrier; waves free-run. 3 blocks/CU.
// ---------------------------------------------------------------------------
template<int STAGE>
__global__ __launch_bounds__(256, 3) void k_conv(
    const unsigned short* __restrict__ Xp,    // [b][258][258][64] bf16 padded
    const float* __restrict__ x_res,          // stage2 residual [b][o][px]
    const float* __restrict__ par,            // stage1 [b][3][HW]
    const unsigned short* __restrict__ W4,    // [b][NS][4][64][8] bf16
    const float* __restrict__ bias,           // [b][64]
    unsigned short* __restrict__ Tp,          // stage1 out [b][258][258][64] bf16
    float* __restrict__ Fout)                 // stage2 out [b][64][HW] f32
{
    constexpr int NS = (STAGE == 1) ? NS1 : NS2;
    __shared__ short xs[SLABR * SLABW * 64];  // 43520 B (aliased as tl in epilogue)

    const int tid = threadIdx.x;
    const int l = tid & 63;
    const int wv = tid >> 6;                  // 0..3; wave owns rows 2wv, 2wv+1
    const int b = blockIdx.y;
    // XCD-aware bijective swizzle (256 blocks = 8 XCD x 32)
    const int bswz = (blockIdx.x & 7) * 32 + (blockIdx.x >> 3);
    const int rblk = bswz >> 3;               // 0..31
    const int cblk = bswz & 7;                // 0..7
    const int gh0 = rblk * 8, w0 = cblk * 32;
    const int ln15 = l & 15, g = l >> 4;

    const char* XbP = (const char*)Xp + (size_t)b * PXP_ * 128;
    const unsigned short* Wb = W4 + (size_t)b * (NS * 2048);

    // per-lane par values (stage1): A-frag mf -> row gh0+2wv+(mf>>1), px w0+16(mf&1)+ln15
    float pvv[3][4];
    if constexpr (STAGE == 1) {
        #pragma unroll
        for (int m = 0; m < 3; ++m)
            #pragma unroll
            for (int mf = 0; mf < 4; ++mf)
                pvv[m][mf] = par[((size_t)b * 3 + m) * HW_ +
                                 (gh0 + 2 * wv + (mf >> 1)) * W_ + w0 + 16 * (mf & 1) + ln15];
    }

    f32x4 acc[4][4];
    #pragma unroll
    for (int mf = 0; mf < 4; ++mf)
        #pragma unroll
        for (int of = 0; of < 4; ++of)
            acc[mf][of] = (f32x4){0.f, 0.f, 0.f, 0.f};

    // ---- async-stage slab [10 rows][34 px][8 chunks]; swizzled src, linear dest
    #pragma unroll
    for (int it = 0; it < 11; ++it) {
        int tau = tid + it * 256;
        if (tau < SLABR * SLABW * 8) {
            int slot = tau & 7;
            int rest = tau >> 3;
            int px = rest % SLABW;
            int row = rest / SLABW;
            int cb = slot ^ (px & 7);
            gload_lds16(XbP + ((size_t)(gh0 + row) * WP_ + (w0 + px)) * 128 + cb * 16,
                        (char*)xs + (size_t)tau * 16);
        }
    }

    // ---- B: fragment-ordered global (L2-resident), 3-deep register pipeline
    short8 breg[3][4];
    auto bload = [&](int s, short8* d) {
        const unsigned short* wp = Wb + (size_t)s * 2048 + l * 8;
        #pragma unroll
        for (int of = 0; of < 4; ++of) d[of] = *(const short8*)(wp + of * 512);
    };
    bload(0, breg[0]);
    bload(1, breg[1]);

    // A-frag loader (call sites fully unrolled -> s compile-time)
    auto aload = [&](int s, short8* d) {
        int dh, dw;
        const int h = s & 1;
        if (STAGE == 1 && s >= 18) { dh = 1; dw = 1; }
        else { const int t = s >> 1; dh = t / 3; dw = t - 3 * dh; }
        #pragma unroll
        for (int mf = 0; mf < 4; ++mf) {
            int idx = 16 * (mf & 1) + ln15 + dw;
            int row = 2 * wv + (mf >> 1) + dh;
            d[mf] = *(const short8*)((const char*)xs + (row * SLABW + idx) * 128 +
                                     ((((h << 2) | g) ^ (idx & 7)) << 4));
        }
    };

    // one-time prologue drain: slab (LDS) + B0/B1 (regs), then the ONLY barrier
    asm volatile("s_waitcnt vmcnt(0)" ::: "memory");
    __builtin_amdgcn_s_barrier();

    #pragma unroll
    for (int s = 0; s < NS; ++s) {
        // pacing fence: B[s] retired, B[s+1] may stay in flight
        if (s >= 2) {
            if (s == NS - 1) asm volatile("s_waitcnt vmcnt(0)" ::: "memory");
            else             asm volatile("s_waitcnt vmcnt(4)" ::: "memory");
        }
        if (s + 2 < NS) bload(s + 2, breg[(s + 2) % 3]);
        short8 a[4];
        aload(s, a);
        if (STAGE == 1 && s >= 18) {   // par-scaled 1x1 expert steps
            const int m = (s - 18) >> 1;
            #pragma unroll
            for (int mf = 0; mf < 4; ++mf)
                #pragma unroll
                for (int j = 0; j < 8; ++j)
                    a[mf][j] = (short)f2bf(bf2f((unsigned short)a[mf][j]) * pvv[m][mf]);
        }
        __builtin_amdgcn_s_setprio(1);
        #pragma unroll
        for (int mf = 0; mf < 4; ++mf)
            #pragma unroll
            for (int of = 0; of < 4; ++of)
                acc[mf][of] = __builtin_amdgcn_mfma_f32_16x16x32_bf16(
                    a[mf], breg[s % 3][of], acc[mf][of], 0, 0, 0);
        __builtin_amdgcn_s_setprio(0);
    }

    if constexpr (STAGE == 1) {
        // ---- epilogue: assemble 128B lines in slab-aliased LDS, store dwordx4
        __syncthreads();                       // all slab reads done
        unsigned short* tl = (unsigned short*)xs;   // [8 rows][32 px][64 o^swz] = 32 KB
        #pragma unroll
        for (int of = 0; of < 4; ++of) {
            int o = of * 16 + ln15;
            float bi = bias[b * 64 + o];
            #pragma unroll
            for (int mf = 0; mf < 4; ++mf) {
                int row_local = 2 * wv + (mf >> 1);
                #pragma unroll
                for (int q = 0; q < 4; ++q) {
                    int px = 16 * (mf & 1) + 4 * g + q;
                    float v = fmaxf(acc[mf][of][q] + bi, 0.f);
                    tl[row_local * 2048 + px * 64 + (o ^ ((px & 7) << 3))] = f2bf(v);
                }
            }
        }
        __syncthreads();
        #pragma unroll
        for (int it = 0; it < 8; ++it) {
            int tau = tid + it * 256;
            int row = tau >> 8;
            int px = (tau >> 3) & 31;
            int j = tau & 7;
            short8 v = *(const short8*)(tl + row * 2048 + px * 64 + ((j ^ (px & 7)) * 8));
            *(short8*)(Tp + ((size_t)b * PXP_ + (size_t)(gh0 + row + 1) * WP_ +
                             (w0 + 1 + px)) * 64 + j * 8) = v;
        }
    } else {
        // ---- epilogue: residual add + f32x4 out
        #pragma unroll
        for (int of = 0; of < 4; ++of) {
            int o = of * 16 + ln15;
            float bi = bias[b * 64 + o];
            #pragma unroll
            for (int mf = 0; mf < 4; ++mf) {
                int gh = gh0 + 2 * wv + (mf >> 1);
                int gw = w0 + 16 * (mf & 1) + g * 4;
                size_t idx = ((size_t)b * 64 + o) * HW_ + gh * W_ + gw;
                f32x4 xv = *(const f32x4*)(x_res + idx);
                f32x4 ov;
                #pragma unroll
                for (int q = 0; q < 4; ++q) ov[q] = xv[q] + acc[mf][of][q] + bi;
                *(f32x4*)(Fout + idx) = ov;
            }
        }
    }
}

extern "C" void kernel_launch(void* const* d_in, const int* in_sizes, int n_in,
                              void* d_out, int out_size, void* d_ws, size_t ws_size,
                              hipStream_t stream) {
    const float* x     = (const float*)d_in[0];
    const float* attn  = (const float*)d_in[1];
    const float* gamma = (const float*)d_in[2];
    const float* par   = (const float*)d_in[3];
    const float* w1    = (const float*)d_in[4];
    const float* b1    = (const float*)d_in[5];
    const float* w2    = (const float*)d_in[6];
    const float* b2    = (const float*)d_in[7];
    const float* w16   = (const float*)d_in[8];
    const float* w168  = (const float*)d_in[9];
    const float* w88   = (const float*)d_in[10];
    float* out = (float*)d_out;

    char* w = (char*)d_ws;
    unsigned short* W4_1 = (unsigned short*)w;                        // 786432 B
    unsigned short* W4_2 = (unsigned short*)(w + 786432);             // 589824 B
    float* bias1 = (float*)(w + 786432 + 589824);                     // 2048 B
    float* bias2 = (float*)(w + 786432 + 589824 + 2048);              // 2048 B
    unsigned short* X1p = (unsigned short*)(w + 1380352);             // 68161536 B
    unsigned short* Tp  = (unsigned short*)(w + 1380352 + 68161536);  // 68161536 B

    k_combine<<<dim3(2692), dim3(256), 0, stream>>>(attn, gamma, w1, b1, w2, b2,
                                                    w16, w168, w88, W4_1, W4_2, bias1, bias2);
    k_border<<<dim3(514), dim3(256), 0, stream>>>(X1p, Tp);
    k_prep<<<dim3(1024, 8), dim3(256), 0, stream>>>(x, X1p);

    dim3 grid(256, 8);
    k_conv<1><<<grid, dim3(256), 0, stream>>>(X1p, nullptr, par, W4_1, bias1, Tp, nullptr);
    k_conv<2><<<grid, dim3(256), 0, stream>>>(Tp, x, nullptr, W4_2, bias2, nullptr, out);
}

// Round 12
// 186.423 us; speedup vs baseline: 1.2838x; 1.2838x over previous
//
#include <hip/hip_runtime.h>
#include <hip/hip_bf16.h>

typedef __attribute__((ext_vector_type(8))) short short8;
typedef __attribute__((ext_vector_type(4))) float f32x4;

#define B_ 8
#define C_ 64
#define H_ 256
#define W_ 256
#define HW_ 65536
#define K_ 10
#define NS1 24
#define NS2 18
#define HP_ 258
#define WP_ 258
#define PXP_ (HP_*WP_)
#define SLABW 34
#define SLABR 10

static __device__ __forceinline__ unsigned short f2bf(float f) {
    __hip_bfloat16 hb = __float2bfloat16(f);
    return *(unsigned short*)&hb;
}
static __device__ __forceinline__ float bf2f(unsigned short u) {
    unsigned v = ((unsigned)u) << 16;
    float f;
    __builtin_memcpy(&f, &v, 4);
    return f;
}

// async global->LDS 16B (dest = wave-uniform base + lane*16, linear in tau)
static __device__ __forceinline__ void gload_lds16(const void* g, void* l) {
    __builtin_amdgcn_global_load_lds(
        (const __attribute__((address_space(1))) unsigned int*)(unsigned long long)g,
        (__attribute__((address_space(3))) unsigned int*)(unsigned int)(unsigned long long)l,
        16, 0, 0);
}

// ---------------------------------------------------------------------------
// Fragment-ordered, gamma-folded, expert-mixed weights + biases.
// W4_1: [b][24 steps][4 of][64 lane][8] bf16 (0..17 conv taps, 18..23 1x1)
// W4_2: [b][18 steps][4][64][8] bf16
// ---------------------------------------------------------------------------
__global__ void k_combine(const float* __restrict__ attn, const float* __restrict__ gamma,
                          const float* __restrict__ w1, const float* __restrict__ b1,
                          const float* __restrict__ w2, const float* __restrict__ b2,
                          const float* __restrict__ w16, const float* __restrict__ w168,
                          const float* __restrict__ w88,
                          unsigned short* __restrict__ W4_1, unsigned short* __restrict__ W4_2,
                          float* __restrict__ bias1, float* __restrict__ bias2) {
    const int N1 = B_ * NS1 * 2048;
    const int N2 = B_ * NS2 * 2048;
    int gid = blockIdx.x * 256 + threadIdx.x;
    if (gid < N1) {
        int b = gid / (NS1 * 2048);
        int r = gid - b * (NS1 * 2048);
        int s = r >> 11;
        int r2 = r & 2047;
        int of = r2 >> 9, l = (r2 >> 3) & 63, j = r2 & 7;
        int o = of * 16 + (l & 15);
        int g = l >> 4;
        float val;
        if (s < 18) {
            int t = s >> 1, h = s & 1;
            int c = h * 32 + g * 8 + j;
            float acc = 0.f;
            #pragma unroll
            for (int k = 0; k < K_; ++k)
                acc += attn[b * K_ + k] * w2[((size_t)(k * 64 + o) * 64 + c) * 9 + t];
            val = acc * gamma[b * 64 + o];
        } else {
            int e = s - 18;
            int m = e >> 1, h = e & 1;
            int c = h * 32 + g * 8 + j;
            const float* wm = (m == 0) ? w16 : (m == 1 ? w168 : w88);
            val = wm[o * 64 + c];
        }
        W4_1[gid] = f2bf(val);
    } else if (gid < N1 + N2) {
        int gid2 = gid - N1;
        int b = gid2 / (NS2 * 2048);
        int r = gid2 - b * (NS2 * 2048);
        int s = r >> 11;
        int r2 = r & 2047;
        int of = r2 >> 9, l = (r2 >> 3) & 63, j = r2 & 7;
        int o = of * 16 + (l & 15);
        int g = l >> 4;
        int t = s >> 1, h = s & 1;
        int c = h * 32 + g * 8 + j;
        float acc = 0.f;
        #pragma unroll
        for (int k = 0; k < K_; ++k)
            acc += attn[b * K_ + k] * w1[((size_t)(k * 64 + o) * 64 + c) * 9 + t];
        W4_2[gid2] = f2bf(acc * gamma[b * 64 + o]);
    } else if (gid < N1 + N2 + 1024) {
        int id2 = gid - N1 - N2;
        int b = id2 >> 7;
        int rest = id2 & 127;
        int o = rest >> 1;
        int which = rest & 1;
        const float* bb = which ? b1 : b2;
        float acc = 0.f;
        #pragma unroll
        for (int k = 0; k < K_; ++k) acc += attn[b * K_ + k] * bb[k * 64 + o];
        float v = acc * gamma[b * 64 + o];
        if (which) bias2[b * 64 + o] = v; else bias1[b * 64 + o] = v;
    }
}

// ---------------------------------------------------------------------------
// Zero halo borders of the padded X1p / Tp buffers.
// ---------------------------------------------------------------------------
__global__ void k_border(unsigned short* __restrict__ X1p, unsigned short* __restrict__ Tp) {
    int gid = blockIdx.x * 256 + threadIdx.x;
    if (gid >= 2 * B_ * 1028 * 8) return;
    int chunk = gid & 7;
    int rest = gid >> 3;
    int p = rest % 1028;
    int rb = rest / 1028;
    int buf = rb & 1, b = rb >> 1;
    int row, col;
    if (p < 258) { row = 0; col = p; }
    else if (p < 516) { row = 257; col = p - 258; }
    else if (p < 772) { row = p - 516 + 1; col = 0; }
    else { row = p - 772 + 1; col = 257; }
    unsigned short* base = (buf ? Tp : X1p) +
        ((size_t)b * PXP_ + (size_t)row * WP_ + col) * 64 + chunk * 8;
    *(short8*)base = (short8){0, 0, 0, 0, 0, 0, 0, 0};
}

// ---------------------------------------------------------------------------
// x [b][64][HW] f32  ->  X1p [b][258][258][64] bf16 (interior only)
// ---------------------------------------------------------------------------
__global__ __launch_bounds__(256) void k_prep(const float* __restrict__ x,
                                              unsigned short* __restrict__ X1p) {
    __shared__ float ls[64][65];
    const int b = blockIdx.y;
    const int px0 = blockIdx.x * 64;
    const int row = px0 >> 8;
    const int col0 = px0 & 255;
    const int t = threadIdx.x;
    for (int e = t; e < 4096; e += 256) {
        int ch = e >> 6, px = e & 63;
        ls[ch][px] = x[((size_t)b * 64 + ch) * HW_ + px0 + px];
    }
    __syncthreads();
    unsigned short* dst = X1p + ((size_t)b * PXP_ + (size_t)(row + 1) * WP_ + col0 + 1) * 64;
    for (int e = t; e < 4096; e += 256) {
        int ch = e & 63, px = e >> 6;
        dst[(size_t)px * 64 + ch] = f2bf(ls[ch][px]);
    }
}

// ---------------------------------------------------------------------------
// Implicit-GEMM conv3x3 via MFMA. Block: 256 thr / 4 FAT waves.
// Wave owns M=64 px (2 img rows x 32 w), N=64 o -> 16 MFMA per K-32 step.
// 2-step phases with CROSS-PHASE register double-buffering: phase p body
// prefetches phase p+1's 8 A-frags + 8 B-frags (ds_read latency hides under
// phase p's 32-MFMA cluster). B: 8-slot x 4KB LDS ring staged by
// global_load_lds at distance 3 phases; counted vmcnt + raw s_barrier
// (1 barrier/phase, never drain-0 mid-loop). A: slab [10][34][64] (43.5 KB).
// ---------------------------------------------------------------------------
template<int STAGE>
__global__ __launch_bounds__(256, 2) void k_conv(
    const unsigned short* __restrict__ Xp,    // [b][258][258][64] bf16 padded
    const float* __restrict__ x_res,          // stage2 residual [b][o][px]
    const float* __restrict__ par,            // stage1 [b][3][HW]
    const unsigned short* __restrict__ W4,    // [b][NS][4][64][8] bf16
    const float* __restrict__ bias,           // [b][64]
    unsigned short* __restrict__ Tp,          // stage1 out [b][258][258][64] bf16
    float* __restrict__ Fout)                 // stage2 out [b][64][HW] f32
{
    constexpr int NS = (STAGE == 1) ? NS1 : NS2;
    constexpr int NPH = NS / 2;
    __shared__ short xs[SLABR * SLABW * 64];  // 43520 B (aliased as tl in epilogue)
    __shared__ short bring[8 * 2048];         // 32768 B B-ring (8 slots x 4KB)

    const int tid = threadIdx.x;
    const int l = tid & 63;
    const int wv = tid >> 6;                  // 0..3; wave owns rows 2wv, 2wv+1
    const int b = blockIdx.y;
    // XCD-aware bijective swizzle (256 blocks = 8 XCD x 32)
    const int bswz = (blockIdx.x & 7) * 32 + (blockIdx.x >> 3);
    const int rblk = bswz >> 3;               // 0..31
    const int cblk = bswz & 7;                // 0..7
    const int gh0 = rblk * 8, w0 = cblk * 32;
    const int ln15 = l & 15, g = l >> 4;

    const char* XbP = (const char*)Xp + (size_t)b * PXP_ * 128;
    const unsigned short* Wb = W4 + (size_t)b * (NS * 2048);

    // per-lane par values (stage1): A-frag mf -> row gh0+2wv+(mf>>1), px w0+16(mf&1)+ln15
    float pvv[3][4];
    if constexpr (STAGE == 1) {
        #pragma unroll
        for (int m = 0; m < 3; ++m)
            #pragma unroll
            for (int mf = 0; mf < 4; ++mf)
                pvv[m][mf] = par[((size_t)b * 3 + m) * HW_ +
                                 (gh0 + 2 * wv + (mf >> 1)) * W_ + w0 + 16 * (mf & 1) + ln15];
    }

    f32x4 acc[4][4];
    #pragma unroll
    for (int mf = 0; mf < 4; ++mf)
        #pragma unroll
        for (int of = 0; of < 4; ++of)
            acc[mf][of] = (f32x4){0.f, 0.f, 0.f, 0.f};

    // ---- async-stage slab [10 rows][34 px][8 chunks]; swizzled src, linear dest
    #pragma unroll
    for (int it = 0; it < 11; ++it) {
        int tau = tid + it * 256;
        if (tau < SLABR * SLABW * 8) {
            int slot = tau & 7;
            int rest = tau >> 3;
            int px = rest % SLABW;
            int row = rest / SLABW;
            int cb = slot ^ (px & 7);
            gload_lds16(XbP + ((size_t)(gh0 + row) * WP_ + (w0 + px)) * 128 + cb * 16,
                        (char*)xs + (size_t)tau * 16);
        }
    }
    // ---- B stage: 4KB/step, 1 gload per thread, 8-slot ring
    auto stage_b = [&](int s) {
        gload_lds16((const char*)Wb + (size_t)s * 4096 + tid * 16,
                    (char*)bring + (s & 7) * 4096 + tid * 16);
    };
    stage_b(0); stage_b(1); stage_b(2); stage_b(3); stage_b(4); stage_b(5);

    // A-frag loader (call sites fully unrolled -> s compile-time)
    auto aload = [&](int s, short8* d) {
        int dh, dw;
        const int h = s & 1;
        if (STAGE == 1 && s >= 18) { dh = 1; dw = 1; }
        else { const int t = s >> 1; dh = t / 3; dw = t - 3 * dh; }
        #pragma unroll
        for (int mf = 0; mf < 4; ++mf) {
            int idx = 16 * (mf & 1) + ln15 + dw;
            int row = 2 * wv + (mf >> 1) + dh;
            d[mf] = *(const short8*)((const char*)xs + (row * SLABW + idx) * 128 +
                                     ((((h << 2) | g) ^ (idx & 7)) << 4));
        }
    };
    // B-frag ring reader
    auto bread = [&](int s, short8* d) {
        const char* rb = (const char*)bring + (s & 7) * 4096 + (size_t)l * 16;
        #pragma unroll
        for (int of = 0; of < 4; ++of) d[of] = *(const short8*)(rb + of * 1024);
    };

    // prologue drain: slab + stages 0..3 landed (4,5 stay in flight)
    asm volatile("s_waitcnt vmcnt(2)" ::: "memory");
    __builtin_amdgcn_s_barrier();

    // phase-0 registers
    short8 aa[2][8], bb[2][8];
    aload(0, &aa[0][0]);
    aload(1, &aa[0][4]);
    bread(0, &bb[0][0]);
    bread(1, &bb[0][4]);

    #pragma unroll
    for (int p = 0; p < NPH; ++p) {
        const int s0 = 2 * p, s1 = 2 * p + 1;
        const int cur = p & 1, nxt = (p + 1) & 1;
        // ---- issue next B-stages (distance 3 phases)
        if (s0 + 6 < NS) stage_b(s0 + 6);
        if (s1 + 6 < NS) stage_b(s1 + 6);
        // ---- prefetch phase p+1 registers (slots landed per fence math)
        if (p + 1 < NPH) {
            aload(s0 + 2, &aa[nxt][0]);
            aload(s1 + 2, &aa[nxt][4]);
            bread(s0 + 2, &bb[nxt][0]);
            bread(s1 + 2, &bb[nxt][4]);
        }
        // ---- par scaling for stage1 expert steps (both steps share m)
        short8 a0[4], a1[4];
        #pragma unroll
        for (int mf = 0; mf < 4; ++mf) { a0[mf] = aa[cur][mf]; a1[mf] = aa[cur][4 + mf]; }
        if (STAGE == 1 && s0 >= 18) {
            const int m = (s0 - 18) >> 1;
            #pragma unroll
            for (int mf = 0; mf < 4; ++mf)
                #pragma unroll
                for (int j = 0; j < 8; ++j) {
                    a0[mf][j] = (short)f2bf(bf2f((unsigned short)a0[mf][j]) * pvv[m][mf]);
                    a1[mf][j] = (short)f2bf(bf2f((unsigned short)a1[mf][j]) * pvv[m][mf]);
                }
        }
        // ---- 32 MFMA (16 indep chains of 2)
        __builtin_amdgcn_s_setprio(1);
        #pragma unroll
        for (int mf = 0; mf < 4; ++mf)
            #pragma unroll
            for (int of = 0; of < 4; ++of)
                acc[mf][of] = __builtin_amdgcn_mfma_f32_16x16x32_bf16(
                    a0[mf], bb[cur][of], acc[mf][of], 0, 0, 0);
        #pragma unroll
        for (int mf = 0; mf < 4; ++mf)
            #pragma unroll
            for (int of = 0; of < 4; ++of)
                acc[mf][of] = __builtin_amdgcn_mfma_f32_16x16x32_bf16(
                    a1[mf], bb[cur][4 + of], acc[mf][of], 0, 0, 0);
        __builtin_amdgcn_s_setprio(0);
        // ---- counted fence + barrier (guarantees stages <= 2p+5 landed)
        if (p + 1 < NPH) {
            const int issued = (2 * p + 8 < NS) ? 2 * p + 8 : NS;
            const int nw0 = issued - (2 * p + 6);
            const int nw = nw0 < 0 ? 0 : nw0;
            if (nw == 2)      asm volatile("s_waitcnt vmcnt(2)" ::: "memory");
            else if (nw == 1) asm volatile("s_waitcnt vmcnt(1)" ::: "memory");
            else              asm volatile("s_waitcnt vmcnt(0)" ::: "memory");
            __builtin_amdgcn_s_barrier();
        }
    }

    if constexpr (STAGE == 1) {
        // ---- epilogue: assemble 128B lines in slab-aliased LDS, store dwordx4
        __syncthreads();                       // all slab/ring reads done
        unsigned short* tl = (unsigned short*)xs;   // [8 rows][32 px][64 o^swz] = 32 KB
        #pragma unroll
        for (int of = 0; of < 4; ++of) {
            int o = of * 16 + ln15;
            float bi = bias[b * 64 + o];
            #pragma unroll
            for (int mf = 0; mf < 4; ++mf) {
                int row_local = 2 * wv + (mf >> 1);
                #pragma unroll
                for (int q = 0; q < 4; ++q) {
                    int px = 16 * (mf & 1) + 4 * g + q;
                    float v = fmaxf(acc[mf][of][q] + bi, 0.f);
                    tl[row_local * 2048 + px * 64 + (o ^ ((px & 7) << 3))] = f2bf(v);
                }
            }
        }
        __syncthreads();
        #pragma unroll
        for (int it = 0; it < 8; ++it) {
            int tau = tid + it * 256;
            int row = tau >> 8;
            int px = (tau >> 3) & 31;
            int j = tau & 7;
            short8 v = *(const short8*)(tl + row * 2048 + px * 64 + ((j ^ (px & 7)) * 8));
            *(short8*)(Tp + ((size_t)b * PXP_ + (size_t)(gh0 + row + 1) * WP_ +
                             (w0 + 1 + px)) * 64 + j * 8) = v;
        }
    } else {
        // ---- epilogue: residual add + f32x4 out
        #pragma unroll
        for (int of = 0; of < 4; ++of) {
            int o = of * 16 + ln15;
            float bi = bias[b * 64 + o];
            #pragma unroll
            for (int mf = 0; mf < 4; ++mf) {
                int gh = gh0 + 2 * wv + (mf >> 1);
                int gw = w0 + 16 * (mf & 1) + g * 4;
                size_t idx = ((size_t)b * 64 + o) * HW_ + gh * W_ + gw;
                f32x4 xv = *(const f32x4*)(x_res + idx);
                f32x4 ov;
                #pragma unroll
                for (int q = 0; q < 4; ++q) ov[q] = xv[q] + acc[mf][of][q] + bi;
                *(f32x4*)(Fout + idx) = ov;
            }
        }
    }
}

extern "C" void kernel_launch(void* const* d_in, const int* in_sizes, int n_in,
                              void* d_out, int out_size, void* d_ws, size_t ws_size,
                              hipStream_t stream) {
    const float* x     = (const float*)d_in[0];
    const float* attn  = (const float*)d_in[1];
    const float* gamma = (const float*)d_in[2];
    const float* par   = (const float*)d_in[3];
    const float* w1    = (const float*)d_in[4];
    const float* b1    = (const float*)d_in[5];
    const float* w2    = (const float*)d_in[6];
    const float* b2    = (const float*)d_in[7];
    const float* w16   = (const float*)d_in[8];
    const float* w168  = (const float*)d_in[9];
    const float* w88   = (const float*)d_in[10];
    float* out = (float*)d_out;

    char* w = (char*)d_ws;
    unsigned short* W4_1 = (unsigned short*)w;                        // 786432 B
    unsigned short* W4_2 = (unsigned short*)(w + 786432);             // 589824 B
    float* bias1 = (float*)(w + 786432 + 589824);                     // 2048 B
    float* bias2 = (float*)(w + 786432 + 589824 + 2048);              // 2048 B
    unsigned short* X1p = (unsigned short*)(w + 1380352);             // 68161536 B
    unsigned short* Tp  = (unsigned short*)(w + 1380352 + 68161536);  // 68161536 B

    k_combine<<<dim3(2692), dim3(256), 0, stream>>>(attn, gamma, w1, b1, w2, b2,
                                                    w16, w168, w88, W4_1, W4_2, bias1, bias2);
    k_border<<<dim3(514), dim3(256), 0, stream>>>(X1p, Tp);
    k_prep<<<dim3(1024, 8), dim3(256), 0, stream>>>(x, X1p);

    dim3 grid(256, 8);
    k_conv<1><<<grid, dim3(256), 0, stream>>>(X1p, nullptr, par, W4_1, bias1, Tp, nullptr);
    k_conv<2><<<grid, dim3(256), 0, stream>>>(Tp, x, nullptr, W4_2, bias2, nullptr, out);
}

// Round 13
// 182.664 us; speedup vs baseline: 1.3103x; 1.0206x over previous
//
#include <hip/hip_runtime.h>
#include <hip/hip_bf16.h>

typedef __attribute__((ext_vector_type(8))) short short8;
typedef __attribute__((ext_vector_type(4))) float f32x4;

#define B_ 8
#define C_ 64
#define H_ 256
#define W_ 256
#define HW_ 65536
#define K_ 10
#define NS1 24
#define NS2 18
#define HP_ 258
#define WP_ 258
#define PXP_ (HP_*WP_)
#define SLABW 34
#define SLABR 6

static __device__ __forceinline__ unsigned short f2bf(float f) {
    __hip_bfloat16 hb = __float2bfloat16(f);
    return *(unsigned short*)&hb;
}
static __device__ __forceinline__ float bf2f(unsigned short u) {
    unsigned v = ((unsigned)u) << 16;
    float f;
    __builtin_memcpy(&f, &v, 4);
    return f;
}

// async global->LDS 16B (dest = wave-uniform base + lane*16, linear in tau)
static __device__ __forceinline__ void gload_lds16(const void* g, void* l) {
    __builtin_amdgcn_global_load_lds(
        (const __attribute__((address_space(1))) unsigned int*)(unsigned long long)g,
        (__attribute__((address_space(3))) unsigned int*)(unsigned int)(unsigned long long)l,
        16, 0, 0);
}

// ---------------------------------------------------------------------------
// Fragment-ordered, gamma-folded, expert-mixed weights + biases.
// W4_1: [b][24 steps][4 of][64 lane][8] bf16 (0..17 conv taps, 18..23 1x1)
// W4_2: [b][18 steps][4][64][8] bf16
// ---------------------------------------------------------------------------
__global__ void k_combine(const float* __restrict__ attn, const float* __restrict__ gamma,
                          const float* __restrict__ w1, const float* __restrict__ b1,
                          const float* __restrict__ w2, const float* __restrict__ b2,
                          const float* __restrict__ w16, const float* __restrict__ w168,
                          const float* __restrict__ w88,
                          unsigned short* __restrict__ W4_1, unsigned short* __restrict__ W4_2,
                          float* __restrict__ bias1, float* __restrict__ bias2) {
    const int N1 = B_ * NS1 * 2048;
    const int N2 = B_ * NS2 * 2048;
    int gid = blockIdx.x * 256 + threadIdx.x;
    if (gid < N1) {
        int b = gid / (NS1 * 2048);
        int r = gid - b * (NS1 * 2048);
        int s = r >> 11;
        int r2 = r & 2047;
        int of = r2 >> 9, l = (r2 >> 3) & 63, j = r2 & 7;
        int o = of * 16 + (l & 15);
        int g = l >> 4;
        float val;
        if (s < 18) {
            int t = s >> 1, h = s & 1;
            int c = h * 32 + g * 8 + j;
            float acc = 0.f;
            #pragma unroll
            for (int k = 0; k < K_; ++k)
                acc += attn[b * K_ + k] * w2[((size_t)(k * 64 + o) * 64 + c) * 9 + t];
            val = acc * gamma[b * 64 + o];
        } else {
            int e = s - 18;
            int m = e >> 1, h = e & 1;
            int c = h * 32 + g * 8 + j;
            const float* wm = (m == 0) ? w16 : (m == 1 ? w168 : w88);
            val = wm[o * 64 + c];
        }
        W4_1[gid] = f2bf(val);
    } else if (gid < N1 + N2) {
        int gid2 = gid - N1;
        int b = gid2 / (NS2 * 2048);
        int r = gid2 - b * (NS2 * 2048);
        int s = r >> 11;
        int r2 = r & 2047;
        int of = r2 >> 9, l = (r2 >> 3) & 63, j = r2 & 7;
        int o = of * 16 + (l & 15);
        int g = l >> 4;
        int t = s >> 1, h = s & 1;
        int c = h * 32 + g * 8 + j;
        float acc = 0.f;
        #pragma unroll
        for (int k = 0; k < K_; ++k)
            acc += attn[b * K_ + k] * w1[((size_t)(k * 64 + o) * 64 + c) * 9 + t];
        W4_2[gid2] = f2bf(acc * gamma[b * 64 + o]);
    } else if (gid < N1 + N2 + 1024) {
        int id2 = gid - N1 - N2;
        int b = id2 >> 7;
        int rest = id2 & 127;
        int o = rest >> 1;
        int which = rest & 1;
        const float* bb = which ? b1 : b2;
        float acc = 0.f;
        #pragma unroll
        for (int k = 0; k < K_; ++k) acc += attn[b * K_ + k] * bb[k * 64 + o];
        float v = acc * gamma[b * 64 + o];
        if (which) bias2[b * 64 + o] = v; else bias1[b * 64 + o] = v;
    }
}

// ---------------------------------------------------------------------------
// Zero halo borders of the padded X1p / Tp buffers.
// ---------------------------------------------------------------------------
__global__ void k_border(unsigned short* __restrict__ X1p, unsigned short* __restrict__ Tp) {
    int gid = blockIdx.x * 256 + threadIdx.x;
    if (gid >= 2 * B_ * 1028 * 8) return;
    int chunk = gid & 7;
    int rest = gid >> 3;
    int p = rest % 1028;
    int rb = rest / 1028;
    int buf = rb & 1, b = rb >> 1;
    int row, col;
    if (p < 258) { row = 0; col = p; }
    else if (p < 516) { row = 257; col = p - 258; }
    else if (p < 772) { row = p - 516 + 1; col = 0; }
    else { row = p - 772 + 1; col = 257; }
    unsigned short* base = (buf ? Tp : X1p) +
        ((size_t)b * PXP_ + (size_t)row * WP_ + col) * 64 + chunk * 8;
    *(short8*)base = (short8){0, 0, 0, 0, 0, 0, 0, 0};
}

// ---------------------------------------------------------------------------
// x [b][64][HW] f32  ->  X1p [b][258][258][64] bf16 (interior only)
// ---------------------------------------------------------------------------
__global__ __launch_bounds__(256) void k_prep(const float* __restrict__ x,
                                              unsigned short* __restrict__ X1p) {
    __shared__ float ls[64][65];
    const int b = blockIdx.y;
    const int px0 = blockIdx.x * 64;
    const int row = px0 >> 8;
    const int col0 = px0 & 255;
    const int t = threadIdx.x;
    for (int e = t; e < 4096; e += 256) {
        int ch = e >> 6, px = e & 63;
        ls[ch][px] = x[((size_t)b * 64 + ch) * HW_ + px0 + px];
    }
    __syncthreads();
    unsigned short* dst = X1p + ((size_t)b * PXP_ + (size_t)(row + 1) * WP_ + col0 + 1) * 64;
    for (int e = t; e < 4096; e += 256) {
        int ch = e & 63, px = e >> 6;
        dst[(size_t)px * 64 + ch] = f2bf(ls[ch][px]);
    }
}

// ---------------------------------------------------------------------------
// Implicit-GEMM conv3x3 via MFMA. Block: 128 thr / 2 FAT waves, tile
// 4 rows x 32 px x 64 o. Small blocks -> 4 independent blocks/CU (38.4 KB
// LDS each): prologue drains and per-step barriers of different blocks
// stagger, hiding latency that barrier-convoyed big blocks could not.
// Wave owns M=64 px (2 rows x 32 px): 16 MFMA per K-32 step.
// A: slab [6][34][64] via global_load_lds. B: 3-slot x 4KB LDS ring,
// stage distance 2, fence vmcnt(2) (never drain-0 mid-loop), s_barrier.
// ---------------------------------------------------------------------------
template<int STAGE>
__global__ __launch_bounds__(128, 2) void k_conv(
    const unsigned short* __restrict__ Xp,    // A source [b][258][258][64] bf16 padded
    const unsigned short* __restrict__ Xres,  // stage2 residual (X1p, bf16 padded)
    const float* __restrict__ par,            // stage1 [b][3][HW]
    const unsigned short* __restrict__ W4,    // [b][NS][4][64][8] bf16
    const float* __restrict__ bias,           // [b][64]
    unsigned short* __restrict__ Tp,          // stage1 out [b][258][258][64] bf16
    float* __restrict__ Fout)                 // stage2 out [b][64][HW] f32
{
    constexpr int NS = (STAGE == 1) ? NS1 : NS2;
    __shared__ short xs[SLABR * SLABW * 64];  // 26112 B (aliased as tl in epilogue)
    __shared__ short bring[3 * 2048];         // 12288 B B-ring (3 slots x 4KB)

    const int tid = threadIdx.x;
    const int l = tid & 63;
    const int wv = tid >> 6;                  // 0..1; wave owns rows 2wv, 2wv+1
    const int b = blockIdx.y;
    // XCD-aware bijective swizzle (512 blocks = 8 XCD x 64)
    const int bswz = (blockIdx.x & 7) * 64 + (blockIdx.x >> 3);
    const int rblk = bswz >> 3;               // 0..63
    const int cblk = bswz & 7;                // 0..7
    const int gh0 = rblk * 4, w0 = cblk * 32;
    const int ln15 = l & 15, g = l >> 4;

    const char* XbP = (const char*)Xp + (size_t)b * PXP_ * 128;
    const unsigned short* Wb = W4 + (size_t)b * (NS * 2048);

    // per-lane par values (stage1): A-frag mf -> row gh0+2wv+(mf>>1), px w0+16(mf&1)+ln15
    float pvv[3][4];
    if constexpr (STAGE == 1) {
        #pragma unroll
        for (int m = 0; m < 3; ++m)
            #pragma unroll
            for (int mf = 0; mf < 4; ++mf)
                pvv[m][mf] = par[((size_t)b * 3 + m) * HW_ +
                                 (gh0 + 2 * wv + (mf >> 1)) * W_ + w0 + 16 * (mf & 1) + ln15];
    }

    f32x4 acc[4][4];
    #pragma unroll
    for (int mf = 0; mf < 4; ++mf)
        #pragma unroll
        for (int of = 0; of < 4; ++of)
            acc[mf][of] = (f32x4){0.f, 0.f, 0.f, 0.f};

    // ---- async-stage slab [6 rows][34 px][8 chunks]; swizzled src, linear dest
    #pragma unroll
    for (int it = 0; it < 13; ++it) {
        int tau = tid + it * 128;
        if (tau < SLABR * SLABW * 8) {
            int slot = tau & 7;
            int rest = tau >> 3;
            int px = rest % SLABW;
            int row = rest / SLABW;
            int cb = slot ^ (px & 7);
            gload_lds16(XbP + ((size_t)(gh0 + row) * WP_ + (w0 + px)) * 128 + cb * 16,
                        (char*)xs + (size_t)tau * 16);
        }
    }
    // ---- B stage: 4KB/step, 2 gloads per thread (128 thr), wave-uniform
    auto stage_b = [&](int s) {
        const char* src = (const char*)Wb + (size_t)s * 4096;
        char* dst = (char*)bring + (s % 3) * 4096;
        gload_lds16(src + tid * 16, dst + tid * 16);
        gload_lds16(src + 2048 + tid * 16, dst + 2048 + tid * 16);
    };
    stage_b(0);
    stage_b(1);

    // A-frag loader (call sites fully unrolled -> s compile-time)
    auto aload = [&](int s, short8* d) {
        int dh, dw;
        const int h = s & 1;
        if (STAGE == 1 && s >= 18) { dh = 1; dw = 1; }
        else { const int t = s >> 1; dh = t / 3; dw = t - 3 * dh; }
        #pragma unroll
        for (int mf = 0; mf < 4; ++mf) {
            int idx = 16 * (mf & 1) + ln15 + dw;
            int row = 2 * wv + (mf >> 1) + dh;
            d[mf] = *(const short8*)((const char*)xs + (row * SLABW + idx) * 128 +
                                     ((((h << 2) | g) ^ (idx & 7)) << 4));
        }
    };

    // prologue: slab + B0 landed; B1 (last 2 gloads) may float
    asm volatile("s_waitcnt vmcnt(2)" ::: "memory");
    __builtin_amdgcn_s_barrier();

    #pragma unroll
    for (int s = 0; s < NS; ++s) {
        // stage step s+2 into slot (s+2)%3 == (s-1)%3 (freed at last barrier)
        if (s + 2 < NS) stage_b(s + 2);
        // B frags from ring slot s%3 (contiguous 1KB per of -> conflict-free)
        const char* rb = (const char*)bring + (s % 3) * 4096 + (size_t)l * 16;
        short8 bf0 = *(const short8*)(rb);
        short8 bf1 = *(const short8*)(rb + 1024);
        short8 bf2 = *(const short8*)(rb + 2048);
        short8 bf3 = *(const short8*)(rb + 3072);
        short8 a[4];
        aload(s, a);
        if (STAGE == 1 && s >= 18) {   // par-scaled 1x1 expert steps
            const int m = (s - 18) >> 1;
            #pragma unroll
            for (int mf = 0; mf < 4; ++mf)
                #pragma unroll
                for (int j = 0; j < 8; ++j)
                    a[mf][j] = (short)f2bf(bf2f((unsigned short)a[mf][j]) * pvv[m][mf]);
        }
        __builtin_amdgcn_s_setprio(1);
        #pragma unroll
        for (int mf = 0; mf < 4; ++mf) {
            acc[mf][0] = __builtin_amdgcn_mfma_f32_16x16x32_bf16(a[mf], bf0, acc[mf][0], 0, 0, 0);
            acc[mf][1] = __builtin_amdgcn_mfma_f32_16x16x32_bf16(a[mf], bf1, acc[mf][1], 0, 0, 0);
            acc[mf][2] = __builtin_amdgcn_mfma_f32_16x16x32_bf16(a[mf], bf2, acc[mf][2], 0, 0, 0);
            acc[mf][3] = __builtin_amdgcn_mfma_f32_16x16x32_bf16(a[mf], bf3, acc[mf][3], 0, 0, 0);
        }
        __builtin_amdgcn_s_setprio(0);
        if (s + 1 < NS) {
            // fence: stage(s+1) landed for ALL waves after the barrier;
            // own stage(s+2) (2 gloads) stays in flight - never drain-0 mid-loop
            if (s + 2 < NS) asm volatile("s_waitcnt vmcnt(2)" ::: "memory");
            else            asm volatile("s_waitcnt vmcnt(0)" ::: "memory");
            __builtin_amdgcn_s_barrier();
        }
    }

    if constexpr (STAGE == 1) {
        // ---- epilogue: assemble 128B lines in slab-aliased LDS, store dwordx4
        __syncthreads();                       // all slab/ring reads done
        unsigned short* tl = (unsigned short*)xs;   // [4 rows][32 px][64 o^swz] = 16 KB
        #pragma unroll
        for (int of = 0; of < 4; ++of) {
            int o = of * 16 + ln15;
            float bi = bias[b * 64 + o];
            #pragma unroll
            for (int mf = 0; mf < 4; ++mf) {
                int row_local = 2 * wv + (mf >> 1);
                #pragma unroll
                for (int q = 0; q < 4; ++q) {
                    int px = 16 * (mf & 1) + 4 * g + q;
                    float v = fmaxf(acc[mf][of][q] + bi, 0.f);
                    tl[row_local * 2048 + px * 64 + (o ^ ((px & 7) << 3))] = f2bf(v);
                }
            }
        }
        __syncthreads();
        #pragma unroll
        for (int it = 0; it < 8; ++it) {
            int tau = tid + it * 128;
            int row = tau >> 8;
            int px = (tau >> 3) & 31;
            int j = tau & 7;
            short8 v = *(const short8*)(tl + row * 2048 + px * 64 + ((j ^ (px & 7)) * 8));
            *(short8*)(Tp + ((size_t)b * PXP_ + (size_t)(gh0 + row + 1) * WP_ +
                             (w0 + 1 + px)) * 64 + j * 8) = v;
        }
    } else {
        // ---- epilogue: residual add from X1p (bf16, L3-hot) + f32x4 out
        const unsigned short* Xr = Xres + (size_t)b * PXP_ * 64;
        #pragma unroll
        for (int of = 0; of < 4; ++of) {
            int o = of * 16 + ln15;
            float bi = bias[b * 64 + o];
            #pragma unroll
            for (int mf = 0; mf < 4; ++mf) {
                int gh = gh0 + 2 * wv + (mf >> 1);
                int gw = w0 + 16 * (mf & 1) + g * 4;
                size_t idx = ((size_t)b * 64 + o) * HW_ + (size_t)gh * W_ + gw;
                const unsigned short* xr =
                    Xr + ((size_t)(gh + 1) * WP_ + (gw + 1)) * 64 + o;
                f32x4 ov;
                #pragma unroll
                for (int q = 0; q < 4; ++q)
                    ov[q] = bf2f(xr[(size_t)q * 64]) + acc[mf][of][q] + bi;
                *(f32x4*)(Fout + idx) = ov;
            }
        }
    }
}

extern "C" void kernel_launch(void* const* d_in, const int* in_sizes, int n_in,
                              void* d_out, int out_size, void* d_ws, size_t ws_size,
                              hipStream_t stream) {
    const float* x     = (const float*)d_in[0];
    const float* attn  = (const float*)d_in[1];
    const float* gamma = (const float*)d_in[2];
    const float* par   = (const float*)d_in[3];
    const float* w1    = (const float*)d_in[4];
    const float* b1    = (const float*)d_in[5];
    const float* w2    = (const float*)d_in[6];
    const float* b2    = (const float*)d_in[7];
    const float* w16   = (const float*)d_in[8];
    const float* w168  = (const float*)d_in[9];
    const float* w88   = (const float*)d_in[10];
    float* out = (float*)d_out;

    char* w = (char*)d_ws;
    unsigned short* W4_1 = (unsigned short*)w;                        // 786432 B
    unsigned short* W4_2 = (unsigned short*)(w + 786432);             // 589824 B
    float* bias1 = (float*)(w + 786432 + 589824);                     // 2048 B
    float* bias2 = (float*)(w + 786432 + 589824 + 2048);              // 2048 B
    unsigned short* X1p = (unsigned short*)(w + 1380352);             // 68161536 B
    unsigned short* Tp  = (unsigned short*)(w + 1380352 + 68161536);  // 68161536 B

    k_combine<<<dim3(2692), dim3(256), 0, stream>>>(attn, gamma, w1, b1, w2, b2,
                                                    w16, w168, w88, W4_1, W4_2, bias1, bias2);
    k_border<<<dim3(514), dim3(256), 0, stream>>>(X1p, Tp);
    k_prep<<<dim3(1024, 8), dim3(256), 0, stream>>>(x, X1p);

    dim3 grid(512, 8);
    k_conv<1><<<grid, dim3(128), 0, stream>>>(X1p, nullptr, par, W4_1, bias1, Tp, nullptr);
    k_conv<2><<<grid, dim3(128), 0, stream>>>(Tp, X1p, par, W4_2, bias2, nullptr, out);
}